// Round 10
// baseline (408.886 us; speedup 1.0000x reference)
//
#include <hip/hip_runtime.h>
#include <math.h>

#define NEG 0.2f
#define CHUNK 16384

__device__ __forceinline__ float lrelu(float v) { return fmaxf(v, NEG * v); }

__device__ __forceinline__ unsigned short f2bf(float f) {
    unsigned u = __float_as_uint(f);
    u = (u + 0x7fffu + ((u >> 16) & 1u)) >> 16;   // RNE
    return (unsigned short)u;
}
__device__ __forceinline__ float bf2f(unsigned short s) {
    return __uint_as_float((unsigned)s << 16);
}

// K1: h1 = x@W1 -> bf16, logits: als -> bf16 (gathered per edge), ald -> fp32.
__global__ __launch_bounds__(256) void k1(const float* __restrict__ x,
        const float* __restrict__ W1, const float* __restrict__ a_src,
        const float* __restrict__ a_dst,
        unsigned short* __restrict__ h1b, unsigned short* __restrict__ als_b,
        float* __restrict__ ald, int N)
{
    __shared__ float Wl[128 * 64];
    __shared__ float xt[128][68];

    const int tid = threadIdx.x;
    const int base = blockIdx.x * 64;

    const float4* Wv = (const float4*)W1;
    float4* Wlv = (float4*)Wl;
    for (int i = tid; i < 128 * 16; i += 256) Wlv[i] = Wv[i];

    for (int idx = tid; idx < 64 * 32; idx += 256) {
        int nl = idx >> 5;
        int k4 = (idx & 31) * 4;
        int n = base + nl;
        float4 v = make_float4(0.f, 0.f, 0.f, 0.f);
        if (n < N) v = *(const float4*)&x[(size_t)n * 128 + k4];
        xt[k4 + 0][nl] = v.x;
        xt[k4 + 1][nl] = v.y;
        xt[k4 + 2][nl] = v.z;
        xt[k4 + 3][nl] = v.w;
    }
    __syncthreads();

    const int wave = tid >> 6, lane = tid & 63;
    const int g = lane >> 4, c = lane & 15;
    const int nl0 = wave * 16 + 4 * g;

    float acc[4][4];
    #pragma unroll
    for (int j = 0; j < 4; ++j)
        #pragma unroll
        for (int t = 0; t < 4; ++t) acc[j][t] = 0.f;

    #pragma unroll 4
    for (int k = 0; k < 128; ++k) {
        float4 wv = *(const float4*)&Wl[k * 64 + 4 * c];
        float4 xv = *(const float4*)&xt[k][nl0];
        const float xs[4] = {xv.x, xv.y, xv.z, xv.w};
        const float wsv[4] = {wv.x, wv.y, wv.z, wv.w};
        #pragma unroll
        for (int j = 0; j < 4; ++j)
            #pragma unroll
            for (int t = 0; t < 4; ++t)
                acc[j][t] = fmaf(xs[j], wsv[t], acc[j][t]);
    }

    float a_s[4], a_d[4];
    #pragma unroll
    for (int t = 0; t < 4; ++t) { a_s[t] = a_src[4 * c + t]; a_d[t] = a_dst[4 * c + t]; }

    #pragma unroll
    for (int j = 0; j < 4; ++j) {
        int n = base + nl0 + j;
        float ps = 0.f, pd = 0.f;
        #pragma unroll
        for (int t = 0; t < 4; ++t) {
            ps = fmaf(acc[j][t], a_s[t], ps);
            pd = fmaf(acc[j][t], a_d[t], pd);
        }
        ps += __shfl_xor(ps, 1, 64);
        pd += __shfl_xor(pd, 1, 64);
        if (n < N) {
            ushort4 hb;
            hb.x = f2bf(acc[j][0]); hb.y = f2bf(acc[j][1]);
            hb.z = f2bf(acc[j][2]); hb.w = f2bf(acc[j][3]);
            *(ushort4*)&h1b[(size_t)n * 64 + 4 * c] = hb;
            if ((c & 1) == 0) {
                als_b[n * 8 + (c >> 1)] = f2bf(ps);
                ald[n * 8 + (c >> 1)] = pd;
            }
        }
    }
}

// ---------- atomic-free CSR build (P1..P4, passed full protocol R5/R6/R7/R9) ----------

__global__ __launch_bounds__(256) void p1(const int* __restrict__ ei, int E, int N,
        int* __restrict__ T, int NB, int NC)
{
    extern __shared__ int hist[];
    int tid = threadIdx.x;
    for (int b = tid; b < NB; b += 256) hist[b] = 0;
    __syncthreads();
    int base = blockIdx.x * CHUNK;
    for (int i = tid; i < CHUNK; i += 256) {
        int e = base + i;
        if (e >= E) break;
        int d = ei[E + e];
        if ((unsigned)d < (unsigned)N) atomicAdd(&hist[d >> 8], 1);
    }
    __syncthreads();
    for (int b = tid; b < NB; b += 256) T[b * NC + blockIdx.x] = hist[b];
}

__global__ __launch_bounds__(256) void p2a(int* __restrict__ T,
        int* __restrict__ total, int NB, int NC)
{
    int wave = threadIdx.x >> 6, lane = threadIdx.x & 63;
    int b = blockIdx.x * 4 + wave;
    if (b >= NB) return;
    int run = 0;
    for (int j0 = 0; j0 < NC; j0 += 64) {
        int j = j0 + lane;
        int orig = (j < NC) ? T[b * NC + j] : 0;
        int v = orig;
        #pragma unroll
        for (int off = 1; off < 64; off <<= 1) {
            int t = __shfl_up(v, off, 64);
            if (lane >= off) v += t;
        }
        if (j < NC) T[b * NC + j] = run + v - orig;
        run += __shfl(v, 63, 64);
    }
    if (lane == 0) total[b] = run;
}

__global__ __launch_bounds__(512) void p2b(const int* __restrict__ total,
        int* __restrict__ bstart, int nb)
{
    __shared__ int s[512];
    int tid = threadIdx.x;
    int run = 0;
    for (int base = 0; base < nb; base += 512) {
        int i = base + tid;
        int orig = (i < nb) ? total[i] : 0;
        s[tid] = orig;
        __syncthreads();
        #pragma unroll
        for (int off = 1; off < 512; off <<= 1) {
            int t = (tid >= off) ? s[tid - off] : 0;
            __syncthreads();
            s[tid] += t;
            __syncthreads();
        }
        if (i < nb) bstart[i] = run + s[tid] - orig;
        int tot = s[511];
        __syncthreads();
        run += tot;
    }
    if (tid == 0) bstart[nb] = run;
}

__global__ __launch_bounds__(256) void p3(const int* __restrict__ ei, int E, int N,
        const int* __restrict__ T, const int* __restrict__ bstart,
        unsigned* __restrict__ tmp, int NB, int NC)
{
    extern __shared__ int cur[];
    int tid = threadIdx.x;
    int j = blockIdx.x;
    for (int b = tid; b < NB; b += 256) cur[b] = bstart[b] + T[b * NC + j];
    __syncthreads();
    int base = j * CHUNK;
    for (int i = tid; i < CHUNK; i += 256) {
        int e = base + i;
        if (e >= E) break;
        int d = ei[E + e];
        if ((unsigned)d >= (unsigned)N) continue;
        int s = ei[e];
        if ((unsigned)s >= (unsigned)N) s = 0;
        int pos = atomicAdd(&cur[d >> 8], 1);
        if ((unsigned)pos < (unsigned)E)
            tmp[pos] = (unsigned)s | ((unsigned)(d & 255) << 24);
    }
}

__global__ __launch_bounds__(256) void p4(const unsigned* __restrict__ tmp,
        const int* __restrict__ bstart,
        int* __restrict__ cnt, int* __restrict__ rowptr, int* __restrict__ csr,
        int N, int E)
{
    __shared__ int hist[256];
    __shared__ int ssc[256];
    __shared__ int cur[256];
    int tid = threadIdx.x;
    int b = blockIdx.x;
    int s0 = bstart[b], s1 = bstart[b + 1];
    if (s0 < 0) s0 = 0; if (s0 > E) s0 = E;
    if (s1 < s0) s1 = s0; if (s1 > E) s1 = E;

    hist[tid] = 0;
    __syncthreads();
    for (int i = s0 + tid; i < s1; i += 256)
        atomicAdd(&hist[tmp[i] >> 24], 1);
    __syncthreads();

    int h = hist[tid];
    ssc[tid] = h;
    __syncthreads();
    #pragma unroll
    for (int off = 1; off < 256; off <<= 1) {
        int t = (tid >= off) ? ssc[tid - off] : 0;
        __syncthreads();
        ssc[tid] += t;
        __syncthreads();
    }
    int excl = ssc[tid] - h;
    int node = b * 256 + tid;
    if (node < N) {
        cnt[node] = h;
        rowptr[node] = s0 + excl;
    }
    cur[tid] = s0 + excl;
    __syncthreads();

    for (int i = s0 + tid; i < s1; i += 256) {
        unsigned v = tmp[i];
        int pos = atomicAdd(&cur[v >> 24], 1);
        if ((unsigned)pos < (unsigned)E) csr[pos] = (int)(v & 0xFFFFFFu);
    }
}

// ---------- fallback atomic build (proven R3/R4) ----------

__global__ __launch_bounds__(256) void kh(const int* __restrict__ ei, int E, int N,
                                          int* __restrict__ cnt)
{
    int e = blockIdx.x * 256 + threadIdx.x;
    if (e >= E) return;
    int d = ei[E + e];
    if ((unsigned)d < (unsigned)N) atomicAdd(&cnt[d], 1);
}

__global__ __launch_bounds__(256) void ka(const int* __restrict__ cnt,
        int* __restrict__ rowptr, int* __restrict__ cursor,
        int* __restrict__ gtotal, int N)
{
    __shared__ int s[256];
    __shared__ int base;
    int tid = threadIdx.x;
    int g = blockIdx.x * 256 + tid;
    int v = (g < N) ? cnt[g] : 0;
    s[tid] = v;
    __syncthreads();
    #pragma unroll
    for (int off = 1; off < 256; off <<= 1) {
        int t = (tid >= off) ? s[tid - off] : 0;
        __syncthreads();
        s[tid] += t;
        __syncthreads();
    }
    if (tid == 255) base = atomicAdd(gtotal, s[255]);
    __syncthreads();
    if (g < N) {
        int r = base + s[tid] - v;
        rowptr[g] = r;
        cursor[g] = r;
    }
}

__global__ __launch_bounds__(256) void kc(const int* __restrict__ ei, int E, int N,
        int* __restrict__ cursor, int* __restrict__ csr)
{
    int e = blockIdx.x * 256 + threadIdx.x;
    if (e >= E) return;
    int s = ei[e];
    int d = ei[E + e];
    if ((unsigned)d >= (unsigned)N) return;
    int p = atomicAdd(&cursor[d], 1);
    if ((unsigned)p < (unsigned)E) csr[p] = s;
}

// ---------- G1 v7: two nodes per wave, barrier-free wave-private staging ----------
// half = lane>>5 owns node nA (half 0) or nB (half 1); slot = lane&31.
// Per 32-edge chunk: phase A stages both nodes' edges densely (all 64 lanes),
// bf16 als gathered as one b128; weights + src offsets go to wave-private LDS
// (in-order LDS pipe => no barrier). Phase B: wave-uniform loops per node,
// 2 edges/step by parity. Global writes: h2a/ald2 guarded by n<N only.
__global__ __launch_bounds__(256) void g1(const int* __restrict__ csr,
        const int* __restrict__ rowptr, const int* __restrict__ cnt,
        const unsigned short* __restrict__ h1b, const unsigned short* __restrict__ als_b,
        const float* __restrict__ ald,
        const float* __restrict__ b1, const float* __restrict__ W2,
        const float* __restrict__ a_src2, const float* __restrict__ a_dst2,
        float2* __restrict__ h2a, float* __restrict__ ald2, int N, int E)
{
    __shared__ float wl[4][2][8 * 33];   // [wave][half][head*33 + slot]
    __shared__ int   sl[4][2][32];       // [wave][half][slot] = src<<5

    const int wave = threadIdx.x >> 6, lane = threadIdx.x & 63;
    const int half = lane >> 5;
    const int slot = lane & 31;
    const int cp = lane & 31;            // col pair for phase B / epilogue
    const int hp = cp >> 2;
    const int s = half;                  // edge parity in phase B

    const int nA = blockIdx.x * 8 + wave * 2;
    const int nB = nA + 1;
    const bool actA = (nA < N), actB = (nB < N);
    const int nA2 = actA ? nA : 0;
    const int nB2 = actB ? nB : 0;
    const int nOwn = half ? nB2 : nA2;

    const unsigned* h1w = (const unsigned*)h1b;
    const float4* ald4 = (const float4*)ald;

    // this lane's half's ald vector (for phase A weights)
    float4 d0 = ald4[nOwn * 2], d1 = ald4[nOwn * 2 + 1];
    float aldv[8] = {d0.x, d0.y, d0.z, d0.w, d1.x, d1.y, d1.z, d1.w};

    int startA = actA ? rowptr[nA2] : 0;
    int cA = actA ? cnt[nA2] : 0;
    if ((unsigned)startA >= (unsigned)E) { startA = 0; cA = 0; }
    if (cA < 0) cA = 0;
    if (startA + cA > E) cA = E - startA;

    int startB = actB ? rowptr[nB2] : 0;
    int cB = actB ? cnt[nB2] : 0;
    if ((unsigned)startB >= (unsigned)E) { startB = 0; cB = 0; }
    if (cB < 0) cB = 0;
    if (startB + cB > E) cB = E - startB;

    const int startOwn = half ? startB : startA;
    const int cOwn = half ? cB : cA;
    const int cmaxW = max(cA, cB);

    float denv[8];
    #pragma unroll
    for (int i = 0; i < 8; ++i) denv[i] = 0.f;
    float a0A = 0.f, a1A = 0.f, a0B = 0.f, a1B = 0.f;

    float* wlwA = wl[wave][0];
    float* wlwB = wl[wave][1];
    float* wlwOwn = half ? wlwB : wlwA;
    int* slwA = sl[wave][0];
    int* slwB = sl[wave][1];
    int* slwOwn = half ? slwB : slwA;

    for (int cbase = 0; cbase < cmaxW; cbase += 32) {
        // ---- phase A: stage this half's chunk (dense: 2 nodes x 32 slots) ----
        int remOwn = cOwn - cbase;
        if (remOwn > 32) remOwn = 32;
        if (remOwn < 0) remOwn = 0;
        int esrc = 0;
        if (slot < remOwn) {
            int t = csr[startOwn + cbase + slot];
            if ((unsigned)t < (unsigned)N) esrc = t;
        }
        uint4 ub = *(const uint4*)&als_b[esrc * 8];
        float wv[8];
        wv[0] = __expf(lrelu(__uint_as_float(ub.x << 16)        + aldv[0]));
        wv[1] = __expf(lrelu(__uint_as_float(ub.x & 0xffff0000u) + aldv[1]));
        wv[2] = __expf(lrelu(__uint_as_float(ub.y << 16)        + aldv[2]));
        wv[3] = __expf(lrelu(__uint_as_float(ub.y & 0xffff0000u) + aldv[3]));
        wv[4] = __expf(lrelu(__uint_as_float(ub.z << 16)        + aldv[4]));
        wv[5] = __expf(lrelu(__uint_as_float(ub.z & 0xffff0000u) + aldv[5]));
        wv[6] = __expf(lrelu(__uint_as_float(ub.w << 16)        + aldv[6]));
        wv[7] = __expf(lrelu(__uint_as_float(ub.w & 0xffff0000u) + aldv[7]));
        if (slot >= remOwn) {
            #pragma unroll
            for (int i = 0; i < 8; ++i) wv[i] = 0.f;
        }
        #pragma unroll
        for (int i = 0; i < 8; ++i) {
            denv[i] += wv[i];
            wlwOwn[i * 33 + slot] = wv[i];
        }
        slwOwn[slot] = esrc << 5;
        // same-wave LDS write->read: LDS pipe is in-order per wave; compiler
        // inserts the lgkmcnt wait for the dependent ds_read results.

        // ---- phase B node A ----
        int remA = cA - cbase;
        if (remA > 32) remA = 32;
        if (remA < 0) remA = 0;
        int stepsA = (remA + 1) >> 1;
        #pragma unroll 4
        for (int i = 0; i < stepsA; ++i) {
            int ge = 2 * i + s;
            float w = wlwA[hp * 33 + ge];
            int soff = slwA[ge];
            unsigned u = h1w[soff + cp];
            a0A = fmaf(w, __uint_as_float(u << 16), a0A);
            a1A = fmaf(w, __uint_as_float(u & 0xffff0000u), a1A);
        }
        // ---- phase B node B ----
        int remB = cB - cbase;
        if (remB > 32) remB = 32;
        if (remB < 0) remB = 0;
        int stepsB = (remB + 1) >> 1;
        #pragma unroll 4
        for (int i = 0; i < stepsB; ++i) {
            int ge = 2 * i + s;
            float w = wlwB[hp * 33 + ge];
            int soff = slwB[ge];
            unsigned u = h1w[soff + cp];
            a0B = fmaf(w, __uint_as_float(u << 16), a0B);
            a1B = fmaf(w, __uint_as_float(u & 0xffff0000u), a1B);
        }
    }

    // den: reduce within each 32-lane half (each half accumulated its own node)
    #pragma unroll
    for (int off = 1; off < 32; off <<= 1) {
        #pragma unroll
        for (int i = 0; i < 8; ++i) denv[i] += __shfl_xor(denv[i], off, 64);
    }
    // select this lane's head value, then exchange across halves
    float q0 = (hp & 1) ? denv[1] : denv[0];
    float q1 = (hp & 1) ? denv[3] : denv[2];
    float q2 = (hp & 1) ? denv[5] : denv[4];
    float q3 = (hp & 1) ? denv[7] : denv[6];
    float r0 = (hp & 2) ? q1 : q0;
    float r1 = (hp & 2) ? q3 : q2;
    float den_own = (hp & 4) ? r1 : r0;
    float den_oth = __shfl_xor(den_own, 32, 64);
    float denA = half ? den_oth : den_own;
    float denB = half ? den_own : den_oth;

    // combine parity halves of accumulators
    a0A += __shfl_xor(a0A, 32, 64);
    a1A += __shfl_xor(a1A, 32, 64);
    a0B += __shfl_xor(a0B, 32, 64);
    a1B += __shfl_xor(a1B, 32, 64);

    // self-loops
    float wsfA = __expf(lrelu(bf2f(als_b[nA2 * 8 + hp]) + ald[nA2 * 8 + hp]));
    float wsfB = __expf(lrelu(bf2f(als_b[nB2 * 8 + hp]) + ald[nB2 * 8 + hp]));
    unsigned uA = h1w[(nA2 << 5) + cp];
    unsigned uB = h1w[(nB2 << 5) + cp];
    denA += wsfA;
    denB += wsfB;
    a0A = fmaf(wsfA, __uint_as_float(uA << 16), a0A);
    a1A = fmaf(wsfA, __uint_as_float(uA & 0xffff0000u), a1A);
    a0B = fmaf(wsfB, __uint_as_float(uB << 16), a0B);
    a1B = fmaf(wsfB, __uint_as_float(uB & 0xffff0000u), a1B);

    // epilogue (both nodes): normalize, +b1, ReLU, dot W2, reduce over cp
    float2 bb = *(const float2*)&b1[2 * cp];
    float2 w2 = *(const float2*)&W2[2 * cp];
    float as2 = a_src2[0], ad2v = a_dst2[0];

    float vA0 = fmaxf(a0A / denA + bb.x, 0.f);
    float vA1 = fmaxf(a1A / denA + bb.y, 0.f);
    float tA = fmaf(vA0, w2.x, vA1 * w2.y);
    float vB0 = fmaxf(a0B / denB + bb.x, 0.f);
    float vB1 = fmaxf(a1B / denB + bb.y, 0.f);
    float tB = fmaf(vB0, w2.x, vB1 * w2.y);
    #pragma unroll
    for (int off = 1; off < 32; off <<= 1) {
        tA += __shfl_xor(tA, off, 64);
        tB += __shfl_xor(tB, off, 64);
    }
    if (lane == 0) {
        if (actA) {
            float2 p; p.x = tA; p.y = tA * as2;
            h2a[nA] = p;
            ald2[nA] = tA * ad2v;
        }
        if (actB) {
            float2 p; p.x = tB; p.y = tB * as2;
            h2a[nB] = p;
            ald2[nB] = tB * ad2v;
        }
    }
}

// G2: fused layer-2 gather + final normalize (proven R4-R9).
__global__ __launch_bounds__(256) void g2(const int* __restrict__ csr,
        const int* __restrict__ rowptr, const int* __restrict__ cnt,
        const float2* __restrict__ h2a, const float* __restrict__ ald2,
        const float* __restrict__ b2, float* __restrict__ out, int N, int E)
{
    int sub = threadIdx.x >> 5;
    int l32 = threadIdx.x & 31;
    int n = blockIdx.x * 8 + sub;
    if (n >= N) return;

    float ad = ald2[n];
    int start = rowptr[n];
    int c = cnt[n];
    if ((unsigned)start >= (unsigned)E) { start = 0; c = 0; }
    if (c < 0) c = 0;
    if (start + c > E) c = E - start;

    float den = 0.f, acc = 0.f;
    for (int i = l32; i < c; i += 32) {
        int src = csr[start + i];
        if ((unsigned)src >= (unsigned)N) src = 0;
        float2 p = h2a[src];
        float w = __expf(lrelu(p.y + ad));
        den += w;
        acc = fmaf(w, p.x, acc);
    }
    #pragma unroll
    for (int off = 1; off < 32; off <<= 1) {
        den += __shfl_xor(den, off, 32);
        acc += __shfl_xor(acc, off, 32);
    }
    if (l32 == 0) {
        float2 p = h2a[n];
        float w0 = __expf(lrelu(p.y + ad));
        out[n] = (acc + w0 * p.x) / (den + w0) + b2[0];
    }
}

extern "C" void kernel_launch(void* const* d_in, const int* in_sizes, int n_in,
                              void* d_out, int out_size, void* d_ws, size_t ws_size,
                              hipStream_t stream)
{
    const float* x   = (const float*)d_in[0];
    const float* W1  = (const float*)d_in[1];
    const float* as1 = (const float*)d_in[2];
    const float* ad1 = (const float*)d_in[3];
    const float* b1  = (const float*)d_in[4];
    const float* W2  = (const float*)d_in[5];
    const float* as2 = (const float*)d_in[6];
    const float* ad2 = (const float*)d_in[7];
    const float* b2  = (const float*)d_in[8];
    const int*   ei  = (const int*)d_in[9];

    int N = in_sizes[0] / 128;
    int E = in_sizes[9] / 2;
    int NB = (N + 255) >> 8;
    int NC = (E + CHUNK - 1) / CHUNK;

    char* wsb = (char*)d_ws;
    size_t off = 0;
    auto alloc = [&](size_t bytes) -> char* {
        char* p = wsb + off;
        off = (off + bytes + 255) & ~(size_t)255;
        return p;
    };

    unsigned short* h1b  = (unsigned short*)alloc((size_t)N * 64 * 2);
    unsigned short* alsb = (unsigned short*)alloc((size_t)N * 8 * 2);
    float* ald    = (float*)alloc((size_t)N * 8 * 4);
    float2* h2a   = (float2*)alloc((size_t)N * 8);
    float* ald2   = (float*)alloc((size_t)N * 4);
    int* cnt      = (int*)alloc((size_t)N * 4);
    int* rowptr   = (int*)alloc((size_t)N * 4);
    int* csr      = (int*)alloc((size_t)E * 4);
    size_t common = off;

    int* T        = (int*)alloc((size_t)NB * NC * 4);
    int* total    = (int*)alloc((size_t)NB * 4);
    int* bstart   = (int*)alloc((size_t)(NB + 1) * 4);
    unsigned* tmp = (unsigned*)alloc((size_t)E * 4);
    size_t need_new = off;

    k1<<<(N + 63) / 64, 256, 0, stream>>>(x, W1, as1, ad1, h1b, alsb, ald, N);

    if (ws_size >= need_new && NB <= 512) {
        size_t lds = (size_t)NB * 4;
        p1<<<NC, 256, lds, stream>>>(ei, E, N, T, NB, NC);
        p2a<<<(NB + 3) / 4, 256, 0, stream>>>(T, total, NB, NC);
        p2b<<<1, 512, 0, stream>>>(total, bstart, NB);
        p3<<<NC, 256, lds, stream>>>(ei, E, N, T, bstart, tmp, NB, NC);
        p4<<<NB, 256, 0, stream>>>(tmp, bstart, cnt, rowptr, csr, N, E);
    } else {
        off = common;
        int* gtotal = (int*)alloc(32);
        int* cursor = (int*)alloc((size_t)N * 4);
        hipMemsetAsync(cnt, 0, (size_t)N * sizeof(int), stream);
        hipMemsetAsync(gtotal, 0, 32, stream);
        kh<<<(E + 255) / 256, 256, 0, stream>>>(ei, E, N, cnt);
        ka<<<(N + 255) / 256, 256, 0, stream>>>(cnt, rowptr, cursor, gtotal, N);
        kc<<<(E + 255) / 256, 256, 0, stream>>>(ei, E, N, cursor, csr);
    }

    g1<<<(N + 7) / 8, 256, 0, stream>>>(csr, rowptr, cnt, h1b, alsb, ald,
                                        b1, W2, as2, ad2, h2a, ald2, N, E);
    g2<<<(N + 7) / 8, 256, 0, stream>>>(csr, rowptr, cnt, h2a, ald2, b2,
                                        (float*)d_out, N, E);
}

// Round 11
// 382.492 us; speedup vs baseline: 1.0690x; 1.0690x over previous
//
#include <hip/hip_runtime.h>
#include <math.h>

#define NEG 0.2f
#define CHUNK 16384

__device__ __forceinline__ float lrelu(float v) { return fmaxf(v, NEG * v); }

__device__ __forceinline__ unsigned short f2bf(float f) {
    unsigned u = __float_as_uint(f);
    u = (u + 0x7fffu + ((u >> 16) & 1u)) >> 16;   // RNE
    return (unsigned short)u;
}
__device__ __forceinline__ float bf2f(unsigned short s) {
    return __uint_as_float((unsigned)s << 16);
}

// K1: h1 = x@W1 -> bf16; logits: als -> bf16 (validated R10), ald -> fp32.
__global__ __launch_bounds__(256) void k1(const float* __restrict__ x,
        const float* __restrict__ W1, const float* __restrict__ a_src,
        const float* __restrict__ a_dst,
        unsigned short* __restrict__ h1b, unsigned short* __restrict__ als_b,
        float* __restrict__ ald, int N)
{
    __shared__ float Wl[128 * 64];
    __shared__ float xt[128][68];

    const int tid = threadIdx.x;
    const int base = blockIdx.x * 64;

    const float4* Wv = (const float4*)W1;
    float4* Wlv = (float4*)Wl;
    for (int i = tid; i < 128 * 16; i += 256) Wlv[i] = Wv[i];

    for (int idx = tid; idx < 64 * 32; idx += 256) {
        int nl = idx >> 5;
        int k4 = (idx & 31) * 4;
        int n = base + nl;
        float4 v = make_float4(0.f, 0.f, 0.f, 0.f);
        if (n < N) v = *(const float4*)&x[(size_t)n * 128 + k4];
        xt[k4 + 0][nl] = v.x;
        xt[k4 + 1][nl] = v.y;
        xt[k4 + 2][nl] = v.z;
        xt[k4 + 3][nl] = v.w;
    }
    __syncthreads();

    const int wave = tid >> 6, lane = tid & 63;
    const int g = lane >> 4, c = lane & 15;
    const int nl0 = wave * 16 + 4 * g;

    float acc[4][4];
    #pragma unroll
    for (int j = 0; j < 4; ++j)
        #pragma unroll
        for (int t = 0; t < 4; ++t) acc[j][t] = 0.f;

    #pragma unroll 4
    for (int k = 0; k < 128; ++k) {
        float4 wv = *(const float4*)&Wl[k * 64 + 4 * c];
        float4 xv = *(const float4*)&xt[k][nl0];
        const float xs[4] = {xv.x, xv.y, xv.z, xv.w};
        const float wsv[4] = {wv.x, wv.y, wv.z, wv.w};
        #pragma unroll
        for (int j = 0; j < 4; ++j)
            #pragma unroll
            for (int t = 0; t < 4; ++t)
                acc[j][t] = fmaf(xs[j], wsv[t], acc[j][t]);
    }

    float a_s[4], a_d[4];
    #pragma unroll
    for (int t = 0; t < 4; ++t) { a_s[t] = a_src[4 * c + t]; a_d[t] = a_dst[4 * c + t]; }

    #pragma unroll
    for (int j = 0; j < 4; ++j) {
        int n = base + nl0 + j;
        float ps = 0.f, pd = 0.f;
        #pragma unroll
        for (int t = 0; t < 4; ++t) {
            ps = fmaf(acc[j][t], a_s[t], ps);
            pd = fmaf(acc[j][t], a_d[t], pd);
        }
        ps += __shfl_xor(ps, 1, 64);
        pd += __shfl_xor(pd, 1, 64);
        if (n < N) {
            ushort4 hb;
            hb.x = f2bf(acc[j][0]); hb.y = f2bf(acc[j][1]);
            hb.z = f2bf(acc[j][2]); hb.w = f2bf(acc[j][3]);
            *(ushort4*)&h1b[(size_t)n * 64 + 4 * c] = hb;
            if ((c & 1) == 0) {
                als_b[n * 8 + (c >> 1)] = f2bf(ps);
                ald[n * 8 + (c >> 1)] = pd;
            }
        }
    }
}

// ---------- atomic-free CSR build (P1..P4, passed full protocol R5/R6/R7/R9) ----------

__global__ __launch_bounds__(256) void p1(const int* __restrict__ ei, int E, int N,
        int* __restrict__ T, int NB, int NC)
{
    extern __shared__ int hist[];
    int tid = threadIdx.x;
    for (int b = tid; b < NB; b += 256) hist[b] = 0;
    __syncthreads();
    int base = blockIdx.x * CHUNK;
    for (int i = tid; i < CHUNK; i += 256) {
        int e = base + i;
        if (e >= E) break;
        int d = ei[E + e];
        if ((unsigned)d < (unsigned)N) atomicAdd(&hist[d >> 8], 1);
    }
    __syncthreads();
    for (int b = tid; b < NB; b += 256) T[b * NC + blockIdx.x] = hist[b];
}

__global__ __launch_bounds__(256) void p2a(int* __restrict__ T,
        int* __restrict__ total, int NB, int NC)
{
    int wave = threadIdx.x >> 6, lane = threadIdx.x & 63;
    int b = blockIdx.x * 4 + wave;
    if (b >= NB) return;
    int run = 0;
    for (int j0 = 0; j0 < NC; j0 += 64) {
        int j = j0 + lane;
        int orig = (j < NC) ? T[b * NC + j] : 0;
        int v = orig;
        #pragma unroll
        for (int off = 1; off < 64; off <<= 1) {
            int t = __shfl_up(v, off, 64);
            if (lane >= off) v += t;
        }
        if (j < NC) T[b * NC + j] = run + v - orig;
        run += __shfl(v, 63, 64);
    }
    if (lane == 0) total[b] = run;
}

__global__ __launch_bounds__(512) void p2b(const int* __restrict__ total,
        int* __restrict__ bstart, int nb)
{
    __shared__ int s[512];
    int tid = threadIdx.x;
    int run = 0;
    for (int base = 0; base < nb; base += 512) {
        int i = base + tid;
        int orig = (i < nb) ? total[i] : 0;
        s[tid] = orig;
        __syncthreads();
        #pragma unroll
        for (int off = 1; off < 512; off <<= 1) {
            int t = (tid >= off) ? s[tid - off] : 0;
            __syncthreads();
            s[tid] += t;
            __syncthreads();
        }
        if (i < nb) bstart[i] = run + s[tid] - orig;
        int tot = s[511];
        __syncthreads();
        run += tot;
    }
    if (tid == 0) bstart[nb] = run;
}

__global__ __launch_bounds__(256) void p3(const int* __restrict__ ei, int E, int N,
        const int* __restrict__ T, const int* __restrict__ bstart,
        unsigned* __restrict__ tmp, int NB, int NC)
{
    extern __shared__ int cur[];
    int tid = threadIdx.x;
    int j = blockIdx.x;
    for (int b = tid; b < NB; b += 256) cur[b] = bstart[b] + T[b * NC + j];
    __syncthreads();
    int base = j * CHUNK;
    for (int i = tid; i < CHUNK; i += 256) {
        int e = base + i;
        if (e >= E) break;
        int d = ei[E + e];
        if ((unsigned)d >= (unsigned)N) continue;
        int s = ei[e];
        if ((unsigned)s >= (unsigned)N) s = 0;
        int pos = atomicAdd(&cur[d >> 8], 1);
        if ((unsigned)pos < (unsigned)E)
            tmp[pos] = (unsigned)s | ((unsigned)(d & 255) << 24);
    }
}

__global__ __launch_bounds__(256) void p4(const unsigned* __restrict__ tmp,
        const int* __restrict__ bstart,
        int* __restrict__ cnt, int* __restrict__ rowptr, int* __restrict__ csr,
        int N, int E)
{
    __shared__ int hist[256];
    __shared__ int ssc[256];
    __shared__ int cur[256];
    int tid = threadIdx.x;
    int b = blockIdx.x;
    int s0 = bstart[b], s1 = bstart[b + 1];
    if (s0 < 0) s0 = 0; if (s0 > E) s0 = E;
    if (s1 < s0) s1 = s0; if (s1 > E) s1 = E;

    hist[tid] = 0;
    __syncthreads();
    for (int i = s0 + tid; i < s1; i += 256)
        atomicAdd(&hist[tmp[i] >> 24], 1);
    __syncthreads();

    int h = hist[tid];
    ssc[tid] = h;
    __syncthreads();
    #pragma unroll
    for (int off = 1; off < 256; off <<= 1) {
        int t = (tid >= off) ? ssc[tid - off] : 0;
        __syncthreads();
        ssc[tid] += t;
        __syncthreads();
    }
    int excl = ssc[tid] - h;
    int node = b * 256 + tid;
    if (node < N) {
        cnt[node] = h;
        rowptr[node] = s0 + excl;
    }
    cur[tid] = s0 + excl;
    __syncthreads();

    for (int i = s0 + tid; i < s1; i += 256) {
        unsigned v = tmp[i];
        int pos = atomicAdd(&cur[v >> 24], 1);
        if ((unsigned)pos < (unsigned)E) csr[pos] = (int)(v & 0xFFFFFFu);
    }
}

// ---------- fallback atomic build (proven R3/R4) ----------

__global__ __launch_bounds__(256) void kh(const int* __restrict__ ei, int E, int N,
                                          int* __restrict__ cnt)
{
    int e = blockIdx.x * 256 + threadIdx.x;
    if (e >= E) return;
    int d = ei[E + e];
    if ((unsigned)d < (unsigned)N) atomicAdd(&cnt[d], 1);
}

__global__ __launch_bounds__(256) void ka(const int* __restrict__ cnt,
        int* __restrict__ rowptr, int* __restrict__ cursor,
        int* __restrict__ gtotal, int N)
{
    __shared__ int s[256];
    __shared__ int base;
    int tid = threadIdx.x;
    int g = blockIdx.x * 256 + tid;
    int v = (g < N) ? cnt[g] : 0;
    s[tid] = v;
    __syncthreads();
    #pragma unroll
    for (int off = 1; off < 256; off <<= 1) {
        int t = (tid >= off) ? s[tid - off] : 0;
        __syncthreads();
        s[tid] += t;
        __syncthreads();
    }
    if (tid == 255) base = atomicAdd(gtotal, s[255]);
    __syncthreads();
    if (g < N) {
        int r = base + s[tid] - v;
        rowptr[g] = r;
        cursor[g] = r;
    }
}

__global__ __launch_bounds__(256) void kc(const int* __restrict__ ei, int E, int N,
        int* __restrict__ cursor, int* __restrict__ csr)
{
    int e = blockIdx.x * 256 + threadIdx.x;
    if (e >= E) return;
    int s = ei[e];
    int d = ei[E + e];
    if ((unsigned)d >= (unsigned)N) return;
    int p = atomicAdd(&cursor[d], 1);
    if ((unsigned)p < (unsigned)E) csr[p] = s;
}

// ---------- G1 v6b: two-phase LDS-staged weights (v6 structure, bf16 als) ----------
// One wave per dst node (4/block). Per 64-edge chunk:
//  Phase A: lane owns edge `lane`: ONE b128 load of als_b[src] (8 bf16),
//           computes all 8 head weights once, accumulates per-lane den
//           partials, stores w (stride-65) + src<<5 to per-wave LDS.
//  Phase B: parity halves; lane cp does 2 ds_read_b32 + 1 dword h1 + 2 fma.
__global__ __launch_bounds__(256) void g1(const int* __restrict__ csr,
        const int* __restrict__ rowptr, const int* __restrict__ cnt,
        const unsigned short* __restrict__ h1b, const unsigned short* __restrict__ als_b,
        const float* __restrict__ ald,
        const float* __restrict__ b1, const float* __restrict__ W2,
        const float* __restrict__ a_src2, const float* __restrict__ a_dst2,
        float2* __restrict__ h2a, float* __restrict__ ald2, int N, int E)
{
    __shared__ float wl[4][8 * 65];     // [wave][head*65 + edge]
    __shared__ int   sl[4][64];         // [wave][edge] = src<<5
    __shared__ int   csh[4];

    const int wave = threadIdx.x >> 6, lane = threadIdx.x & 63;
    const int n = blockIdx.x * 4 + wave;
    const bool active = (n < N);
    const int n2 = active ? n : 0;

    const int s = lane >> 5;
    const int cp = lane & 31;
    const int hp = cp >> 2;

    const unsigned* h1w = (const unsigned*)h1b;
    const float4* ald4 = (const float4*)ald;

    float4 d0 = ald4[n2 * 2], d1 = ald4[n2 * 2 + 1];
    float aldv[8] = {d0.x, d0.y, d0.z, d0.w, d1.x, d1.y, d1.z, d1.w};

    float denv[8];
    #pragma unroll
    for (int i = 0; i < 8; ++i) denv[i] = 0.f;
    float acc0 = 0.f, acc1 = 0.f;

    int start = active ? rowptr[n2] : 0;
    int c = active ? cnt[n2] : 0;
    if ((unsigned)start >= (unsigned)E) { start = 0; c = 0; }
    if (c < 0) c = 0;
    if (start + c > E) c = E - start;

    if (lane == 0) csh[wave] = c;
    __syncthreads();
    int cmax = max(max(csh[0], csh[1]), max(csh[2], csh[3]));

    float* wlw = wl[wave];
    int* slw = sl[wave];

    for (int cbase = 0; cbase < cmax; cbase += 64) {
        int rem = c - cbase;
        if (rem > 64) rem = 64;
        if (rem < 0) rem = 0;

        // ---- phase A ----
        int esrc = 0;
        if (lane < rem) {
            int t = csr[start + cbase + lane];
            if ((unsigned)t < (unsigned)N) esrc = t;
        }
        uint4 ub = *(const uint4*)&als_b[esrc * 8];
        float wv[8];
        wv[0] = __expf(lrelu(__uint_as_float(ub.x << 16)         + aldv[0]));
        wv[1] = __expf(lrelu(__uint_as_float(ub.x & 0xffff0000u) + aldv[1]));
        wv[2] = __expf(lrelu(__uint_as_float(ub.y << 16)         + aldv[2]));
        wv[3] = __expf(lrelu(__uint_as_float(ub.y & 0xffff0000u) + aldv[3]));
        wv[4] = __expf(lrelu(__uint_as_float(ub.z << 16)         + aldv[4]));
        wv[5] = __expf(lrelu(__uint_as_float(ub.z & 0xffff0000u) + aldv[5]));
        wv[6] = __expf(lrelu(__uint_as_float(ub.w << 16)         + aldv[6]));
        wv[7] = __expf(lrelu(__uint_as_float(ub.w & 0xffff0000u) + aldv[7]));
        if (lane >= rem) {
            #pragma unroll
            for (int i = 0; i < 8; ++i) wv[i] = 0.f;
        }
        #pragma unroll
        for (int i = 0; i < 8; ++i) {
            denv[i] += wv[i];
            wlw[i * 65 + lane] = wv[i];
        }
        slw[lane] = esrc << 5;
        __syncthreads();

        // ---- phase B ----
        int steps = (rem + 1) >> 1;
        #pragma unroll 4
        for (int i = 0; i < steps; ++i) {
            int ge = 2 * i + s;
            float w = wlw[hp * 65 + ge];
            int soff = slw[ge];
            unsigned u = h1w[soff + cp];
            acc0 = fmaf(w, __uint_as_float(u << 16), acc0);
            acc1 = fmaf(w, __uint_as_float(u & 0xffff0000u), acc1);
        }
        __syncthreads();
    }

    // reduce den partials across all 64 lanes (element-wise tree)
    #pragma unroll
    for (int off = 1; off < 64; off <<= 1) {
        #pragma unroll
        for (int i = 0; i < 8; ++i) denv[i] += __shfl_xor(denv[i], off, 64);
    }
    float q0 = (hp & 1) ? denv[1] : denv[0];
    float q1 = (hp & 1) ? denv[3] : denv[2];
    float q2 = (hp & 1) ? denv[5] : denv[4];
    float q3 = (hp & 1) ? denv[7] : denv[6];
    float r0 = (hp & 2) ? q1 : q0;
    float r1 = (hp & 2) ? q3 : q2;
    float den = (hp & 4) ? r1 : r0;

    // combine the two edge-parity halves
    acc0 += __shfl_xor(acc0, 32, 64);
    acc1 += __shfl_xor(acc1, 32, 64);

    // self-loop
    float wsf = __expf(lrelu(bf2f(als_b[n2 * 8 + hp]) + aldv[hp]));
    unsigned un = h1w[(n2 << 5) + cp];
    den += wsf;
    acc0 = fmaf(wsf, __uint_as_float(un << 16), acc0);
    acc1 = fmaf(wsf, __uint_as_float(un & 0xffff0000u), acc1);

    // epilogue: normalize, +b1, ReLU, dot W2, reduce across wave
    float2 bb = *(const float2*)&b1[2 * cp];
    float2 w2 = *(const float2*)&W2[2 * cp];
    float v0 = fmaxf(acc0 / den + bb.x, 0.f);
    float v1 = fmaxf(acc1 / den + bb.y, 0.f);
    float t = fmaf(v0, w2.x, v1 * w2.y);
    #pragma unroll
    for (int off = 1; off < 32; off <<= 1) t += __shfl_xor(t, off, 64);
    if (active && lane == 0) {
        float2 p;
        p.x = t;
        p.y = t * a_src2[0];
        h2a[n] = p;
        ald2[n] = t * a_dst2[0];
    }
}

// G2: fused layer-2 gather + final normalize (proven R4-R10).
__global__ __launch_bounds__(256) void g2(const int* __restrict__ csr,
        const int* __restrict__ rowptr, const int* __restrict__ cnt,
        const float2* __restrict__ h2a, const float* __restrict__ ald2,
        const float* __restrict__ b2, float* __restrict__ out, int N, int E)
{
    int sub = threadIdx.x >> 5;
    int l32 = threadIdx.x & 31;
    int n = blockIdx.x * 8 + sub;
    if (n >= N) return;

    float ad = ald2[n];
    int start = rowptr[n];
    int c = cnt[n];
    if ((unsigned)start >= (unsigned)E) { start = 0; c = 0; }
    if (c < 0) c = 0;
    if (start + c > E) c = E - start;

    float den = 0.f, acc = 0.f;
    for (int i = l32; i < c; i += 32) {
        int src = csr[start + i];
        if ((unsigned)src >= (unsigned)N) src = 0;
        float2 p = h2a[src];
        float w = __expf(lrelu(p.y + ad));
        den += w;
        acc = fmaf(w, p.x, acc);
    }
    #pragma unroll
    for (int off = 1; off < 32; off <<= 1) {
        den += __shfl_xor(den, off, 32);
        acc += __shfl_xor(acc, off, 32);
    }
    if (l32 == 0) {
        float2 p = h2a[n];
        float w0 = __expf(lrelu(p.y + ad));
        out[n] = (acc + w0 * p.x) / (den + w0) + b2[0];
    }
}

extern "C" void kernel_launch(void* const* d_in, const int* in_sizes, int n_in,
                              void* d_out, int out_size, void* d_ws, size_t ws_size,
                              hipStream_t stream)
{
    const float* x   = (const float*)d_in[0];
    const float* W1  = (const float*)d_in[1];
    const float* as1 = (const float*)d_in[2];
    const float* ad1 = (const float*)d_in[3];
    const float* b1  = (const float*)d_in[4];
    const float* W2  = (const float*)d_in[5];
    const float* as2 = (const float*)d_in[6];
    const float* ad2 = (const float*)d_in[7];
    const float* b2  = (const float*)d_in[8];
    const int*   ei  = (const int*)d_in[9];

    int N = in_sizes[0] / 128;
    int E = in_sizes[9] / 2;
    int NB = (N + 255) >> 8;
    int NC = (E + CHUNK - 1) / CHUNK;

    char* wsb = (char*)d_ws;
    size_t off = 0;
    auto alloc = [&](size_t bytes) -> char* {
        char* p = wsb + off;
        off = (off + bytes + 255) & ~(size_t)255;
        return p;
    };

    unsigned short* h1b  = (unsigned short*)alloc((size_t)N * 64 * 2);
    unsigned short* alsb = (unsigned short*)alloc((size_t)N * 8 * 2);
    float* ald    = (float*)alloc((size_t)N * 8 * 4);
    float2* h2a   = (float2*)alloc((size_t)N * 8);
    float* ald2   = (float*)alloc((size_t)N * 4);
    int* cnt      = (int*)alloc((size_t)N * 4);
    int* rowptr   = (int*)alloc((size_t)N * 4);
    int* csr      = (int*)alloc((size_t)E * 4);
    size_t common = off;

    int* T        = (int*)alloc((size_t)NB * NC * 4);
    int* total    = (int*)alloc((size_t)NB * 4);
    int* bstart   = (int*)alloc((size_t)(NB + 1) * 4);
    unsigned* tmp = (unsigned*)alloc((size_t)E * 4);
    size_t need_new = off;

    k1<<<(N + 63) / 64, 256, 0, stream>>>(x, W1, as1, ad1, h1b, alsb, ald, N);

    if (ws_size >= need_new && NB <= 512) {
        size_t lds = (size_t)NB * 4;
        p1<<<NC, 256, lds, stream>>>(ei, E, N, T, NB, NC);
        p2a<<<(NB + 3) / 4, 256, 0, stream>>>(T, total, NB, NC);
        p2b<<<1, 512, 0, stream>>>(total, bstart, NB);
        p3<<<NC, 256, lds, stream>>>(ei, E, N, T, bstart, tmp, NB, NC);
        p4<<<NB, 256, 0, stream>>>(tmp, bstart, cnt, rowptr, csr, N, E);
    } else {
        off = common;
        int* gtotal = (int*)alloc(32);
        int* cursor = (int*)alloc((size_t)N * 4);
        hipMemsetAsync(cnt, 0, (size_t)N * sizeof(int), stream);
        hipMemsetAsync(gtotal, 0, 32, stream);
        kh<<<(E + 255) / 256, 256, 0, stream>>>(ei, E, N, cnt);
        ka<<<(N + 255) / 256, 256, 0, stream>>>(cnt, rowptr, cursor, gtotal, N);
        kc<<<(E + 255) / 256, 256, 0, stream>>>(ei, E, N, cursor, csr);
    }

    g1<<<(N + 3) / 4, 256, 0, stream>>>(csr, rowptr, cnt, h1b, alsb, ald,
                                        b1, W2, as2, ad2, h2a, ald2, N, E);
    g2<<<(N + 7) / 8, 256, 0, stream>>>(csr, rowptr, cnt, h2a, ald2, b2,
                                        (float*)d_out, N, E);
}